// Round 2
// baseline (1455.701 us; speedup 1.0000x reference)
//
#include <hip/hip_runtime.h>
#include <hip/hip_bf16.h>
#include <math.h>
#include <stdint.h>

#define T_TOK 131072   // 32 * 64 * 64 tokens
#define CDIM 384
#define FFDIM 1536

typedef __attribute__((ext_vector_type(4))) float f32x4;
typedef __attribute__((ext_vector_type(8))) short s16x8;

// ---------- helpers ----------

__device__ inline short f2bf(float f) {   // round-to-nearest-even f32 -> bf16 bits
  union { float f; unsigned u; } v; v.f = f;
  unsigned r = v.u + 0x7FFFu + ((v.u >> 16) & 1u);
  return (short)(r >> 16);
}

__device__ inline unsigned f2bf2(float lo, float hi) {  // pack 2 bf16 into u32
  return (unsigned)(unsigned short)f2bf(lo) | ((unsigned)(unsigned short)f2bf(hi) << 16);
}

// window-layout token index -> original (B, H*W) row index
__device__ inline int win_to_orig(int t) {
  int w = t >> 6, l = t & 63;
  int b = w >> 6, wh = (w >> 3) & 7, ww = w & 7;
  int r = l >> 3, c = l & 7;
  return (b << 12) + ((wh << 3) + r) * 64 + (ww << 3) + c;
}

__device__ inline void gload_lds16(const void* g, void* l) {
  __builtin_amdgcn_global_load_lds(
      (const __attribute__((address_space(1))) void*)g,
      (__attribute__((address_space(3))) void*)l, 16, 0, 0);
}

__device__ inline float red64(float v) {
  #pragma unroll
  for (int m = 1; m < 64; m <<= 1) v += __shfl_xor(v, m, 64);
  return v;
}

// ---------- weight prep ----------

// Weff[o][c] = W[o][c]*g[c] (bf16); beff[o] = bias[o] + sum_c W[o][c]*bln[c]
__global__ __launch_bounds__(64) void k_fold(
    const float* __restrict__ W, const float* __restrict__ bias,
    const float* __restrict__ g, const float* __restrict__ bln,
    short* __restrict__ Weff, float* __restrict__ beff) {
  int o = blockIdx.x, lane = threadIdx.x;
  const float* wr = W + (size_t)o * CDIM;
  float s = 0.f;
  #pragma unroll
  for (int j = 0; j < 6; ++j) {
    int c = j * 64 + lane;
    float wv = wr[c];
    Weff[(size_t)o * CDIM + c] = f2bf(wv * g[c]);
    s += wv * bln[c];
  }
  s = red64(s);
  if (lane == 0) beff[o] = bias[o] + s;
}

__global__ void k_conv(const float* __restrict__ a, short* __restrict__ o, int n) {
  int i = blockIdx.x * 256 + threadIdx.x;
  if (i < n) o[i] = f2bf(a[i]);
}

// ---------- K1: LN1 (window gather) + shared LN-hat for q/k/v ----------

__global__ __launch_bounds__(256) void k1_ln(
    const float* __restrict__ x, const float* __restrict__ g1, const float* __restrict__ b1,
    float* __restrict__ win, short* __restrict__ win_hat) {
  int wid = threadIdx.x >> 6, lane = threadIdx.x & 63;
  int t = blockIdx.x * 4 + wid;
  int orig = win_to_orig(t);
  const float* xr = x + (size_t)orig * CDIM;
  float2 v[3];
  float s = 0.f;
  #pragma unroll
  for (int j = 0; j < 3; ++j) {
    v[j] = *(const float2*)&xr[j * 128 + lane * 2];
    s += v[j].x + v[j].y;
  }
  s = red64(s);
  float m = s * (1.f / 384.f);
  float s2 = 0.f;
  #pragma unroll
  for (int j = 0; j < 3; ++j) {
    float dx = v[j].x - m, dy = v[j].y - m;
    s2 += dx * dx + dy * dy;
  }
  s2 = red64(s2);
  float rstd = rsqrtf(s2 * (1.f / 384.f) + 1e-5f);
  float2 wv[3]; float sw = 0.f;
  #pragma unroll
  for (int j = 0; j < 3; ++j) {
    int c = j * 128 + lane * 2;
    float2 g = *(const float2*)&g1[c];
    float2 b = *(const float2*)&b1[c];
    wv[j].x = (v[j].x - m) * rstd * g.x + b.x;
    wv[j].y = (v[j].y - m) * rstd * g.y + b.y;
    sw += wv[j].x + wv[j].y;
  }
  sw = red64(sw);
  float m2 = sw * (1.f / 384.f);
  float s2b = 0.f;
  #pragma unroll
  for (int j = 0; j < 3; ++j) {
    float dx = wv[j].x - m2, dy = wv[j].y - m2;
    s2b += dx * dx + dy * dy;
  }
  s2b = red64(s2b);
  float rstd2 = rsqrtf(s2b * (1.f / 384.f) + 1e-5f);
  float* wr = win + (size_t)t * CDIM;
  short* whr = win_hat + (size_t)t * CDIM;
  #pragma unroll
  for (int j = 0; j < 3; ++j) {
    int c = j * 128 + lane * 2;
    *(float2*)&wr[c] = wv[j];
    *(unsigned*)&whr[c] = f2bf2((wv[j].x - m2) * rstd2, (wv[j].y - m2) * rstd2);
  }
}

// ---------- generic 128x128 MFMA GEMM:  C[M,N] = A[M,K] @ B[N,K]^T ----------
// EPI 0: bf16 out = acc + bias           (QKV)
// EPI 1: bf16 out = gelu(acc + bias)     (FFN1)
// EPI 2: f32 d_out[perm(row)] = acc + bias + resid[row]   (FFN2)

template <int K, int EPI, int LDO>
__global__ __launch_bounds__(256, 2) void gemm128(
    const short* __restrict__ A, const short* __restrict__ B,
    const float* __restrict__ bias, void* __restrict__ out,
    const float* __restrict__ resid) {
  __shared__ short Ash[128 * 64];
  __shared__ short Bsh[128 * 64];
  int tid = threadIdx.x;
  int wid = tid >> 6, lane = tid & 63;
  int l15 = lane & 15, l4 = lane >> 4;
  int row0 = blockIdx.y * 128, col0 = blockIdx.x * 128;
  int wr = (wid >> 1) * 64, wc = (wid & 1) * 64;
  f32x4 zz = {0.f, 0.f, 0.f, 0.f};
  f32x4 acc[4][4];
  #pragma unroll
  for (int a = 0; a < 4; ++a)
    #pragma unroll
    for (int b = 0; b < 4; ++b) acc[a][b] = zz;

  for (int k0 = 0; k0 < K; k0 += 64) {
    #pragma unroll
    for (int j = 0; j < 4; ++j) {
      int c = (wid * 4 + j) * 64 + lane;     // chunk id 0..1023 (16B chunks)
      int r = c >> 3, kc = c & 7;
      int kcs = kc ^ (r & 7);                // source pre-swizzle (rule 21)
      gload_lds16(A + (size_t)(row0 + r) * K + k0 + kcs * 8, &Ash[(wid * 4 + j) * 512]);
      gload_lds16(B + (size_t)(col0 + r) * K + k0 + kcs * 8, &Bsh[(wid * 4 + j) * 512]);
    }
    __syncthreads();
    #pragma unroll
    for (int kk = 0; kk < 2; ++kk) {
      s16x8 af[4], bfr[4];
      #pragma unroll
      for (int mi = 0; mi < 4; ++mi) {
        int rr = wr + mi * 16 + l15;
        int ch = (kk * 4 + l4) ^ (rr & 7);
        af[mi] = *(const s16x8*)&Ash[rr * 64 + ch * 8];
      }
      #pragma unroll
      for (int ni = 0; ni < 4; ++ni) {
        int rr = wc + ni * 16 + l15;
        int ch = (kk * 4 + l4) ^ (rr & 7);
        bfr[ni] = *(const s16x8*)&Bsh[rr * 64 + ch * 8];
      }
      #pragma unroll
      for (int mi = 0; mi < 4; ++mi)
        #pragma unroll
        for (int ni = 0; ni < 4; ++ni)
          acc[mi][ni] = __builtin_amdgcn_mfma_f32_16x16x32_bf16(af[mi], bfr[ni], acc[mi][ni], 0, 0, 0);
    }
    __syncthreads();
  }

  #pragma unroll
  for (int mi = 0; mi < 4; ++mi)
    #pragma unroll
    for (int r = 0; r < 4; ++r) {
      int row = row0 + wr + mi * 16 + l4 * 4 + r;
      int orow = (EPI == 2) ? win_to_orig(row) : row;
      #pragma unroll
      for (int ni = 0; ni < 4; ++ni) {
        int col = col0 + wc + ni * 16 + l15;
        float v = acc[mi][ni][r] + bias[col];
        if constexpr (EPI == 0) {
          ((short*)out)[(size_t)row * LDO + col] = f2bf(v);
        } else if constexpr (EPI == 1) {
          float gl = 0.5f * v * (1.f + erff(v * 0.70710678118654752f));
          ((short*)out)[(size_t)row * LDO + col] = f2bf(gl);
        } else {
          v += resid[(size_t)row * CDIM + col];
          ((float*)out)[(size_t)orow * CDIM + col] = v;
        }
      }
    }
}

// ---------- K3: windowed attention, one wave = one (window, head) ----------

__global__ __launch_bounds__(256, 2) void k3_attn(
    const short* __restrict__ qkv, short* __restrict__ o) {
  __shared__ short Psh[4][64 * 72];   // P, padded stride 72 (bank-conflict-free)
  __shared__ short Vsh[4][32 * 72];   // V^T
  int tid = threadIdx.x, wid = tid >> 6, lane = tid & 63;
  int l15 = lane & 15, l4 = lane >> 4;
  int w = blockIdx.x / 3, q3 = blockIdx.x % 3;
  int h = q3 * 4 + wid;
  const short* base = qkv + (size_t)w * 64 * 1152;

  s16x8 qf[4], kf[4];
  #pragma unroll
  for (int i = 0; i < 4; ++i) {
    qf[i] = *(const s16x8*)&base[(size_t)(i * 16 + l15) * 1152 + h * 32 + l4 * 8];
    kf[i] = *(const s16x8*)&base[(size_t)(i * 16 + l15) * 1152 + 384 + h * 32 + l4 * 8];
  }
  f32x4 zz = {0.f, 0.f, 0.f, 0.f};
  f32x4 s[4][4];
  #pragma unroll
  for (int a = 0; a < 4; ++a)
    #pragma unroll
    for (int b = 0; b < 4; ++b) s[a][b] = zz;
  #pragma unroll
  for (int mi = 0; mi < 4; ++mi)
    #pragma unroll
    for (int ni = 0; ni < 4; ++ni)
      s[mi][ni] = __builtin_amdgcn_mfma_f32_16x16x32_bf16(qf[mi], kf[ni], s[mi][ni], 0, 0, 0);

  const float scale = 0.17677669529663687f;  // 1/sqrt(32)
  float rs[4][4];
  #pragma unroll
  for (int mi = 0; mi < 4; ++mi)
    #pragma unroll
    for (int r = 0; r < 4; ++r) {
      float mx = -1e30f;
      #pragma unroll
      for (int ni = 0; ni < 4; ++ni) { s[mi][ni][r] *= scale; mx = fmaxf(mx, s[mi][ni][r]); }
      #pragma unroll
      for (int m = 1; m < 16; m <<= 1) mx = fmaxf(mx, __shfl_xor(mx, m, 64));
      float sum = 0.f;
      int prow = mi * 16 + l4 * 4 + r;
      #pragma unroll
      for (int ni = 0; ni < 4; ++ni) {
        float p = __expf(s[mi][ni][r] - mx);
        sum += p;
        Psh[wid][prow * 72 + ni * 16 + l15] = f2bf(p);
      }
      #pragma unroll
      for (int m = 1; m < 16; m <<= 1) sum += __shfl_xor(sum, m, 64);
      rs[mi][r] = 1.f / sum;
    }

  {  // stage V transposed: Vsh[d][t]
    const short* vr = base + (size_t)lane * 1152 + 768 + h * 32;
    s16x8 v0 = *(const s16x8*)vr;
    s16x8 v1 = *(const s16x8*)(vr + 8);
    s16x8 v2 = *(const s16x8*)(vr + 16);
    s16x8 v3 = *(const s16x8*)(vr + 24);
    #pragma unroll
    for (int d = 0; d < 8; ++d) {
      Vsh[wid][d * 72 + lane] = v0[d];
      Vsh[wid][(d + 8) * 72 + lane] = v1[d];
      Vsh[wid][(d + 16) * 72 + lane] = v2[d];
      Vsh[wid][(d + 24) * 72 + lane] = v3[d];
    }
  }
  __syncthreads();

  f32x4 oacc[4][2];
  #pragma unroll
  for (int a = 0; a < 4; ++a) { oacc[a][0] = zz; oacc[a][1] = zz; }
  #pragma unroll
  for (int kk = 0; kk < 2; ++kk) {
    s16x8 pa[4], vb[2];
    #pragma unroll
    for (int mi = 0; mi < 4; ++mi)
      pa[mi] = *(const s16x8*)&Psh[wid][(mi * 16 + l15) * 72 + kk * 32 + l4 * 8];
    #pragma unroll
    for (int ni = 0; ni < 2; ++ni)
      vb[ni] = *(const s16x8*)&Vsh[wid][(ni * 16 + l15) * 72 + kk * 32 + l4 * 8];
    #pragma unroll
    for (int mi = 0; mi < 4; ++mi)
      #pragma unroll
      for (int ni = 0; ni < 2; ++ni)
        oacc[mi][ni] = __builtin_amdgcn_mfma_f32_16x16x32_bf16(pa[mi], vb[ni], oacc[mi][ni], 0, 0, 0);
  }
  #pragma unroll
  for (int mi = 0; mi < 4; ++mi)
    #pragma unroll
    for (int ni = 0; ni < 2; ++ni)
      #pragma unroll
      for (int r = 0; r < 4; ++r) {
        int row = mi * 16 + l4 * 4 + r;
        float val = oacc[mi][ni][r] * rs[mi][r];
        o[((size_t)w * 64 + row) * 384 + h * 32 + ni * 16 + l15] = f2bf(val);
      }
}

// ---------- K4: out_proj GEMM (BN=384 full row) + nout LN + x-residual + norm2-hat ----------
// NOTE: win and x_new ALIAS (in-place). Safe: each (row,col) is read+written by
// exactly one thread, and every x_new store data-depends on all win loads of its
// row (via mean/rstd). No __restrict__ on these two params.

__global__ __launch_bounds__(256, 2) void k4_outproj(
    const short* __restrict__ A, const short* __restrict__ B,
    const float* __restrict__ bout, const float* __restrict__ g_nout, const float* __restrict__ b_nout,
    const float* win, const float* __restrict__ x,
    float* x_new, short* __restrict__ xhat2) {
  __shared__ short Ash[64 * 64];
  __shared__ short Bsh[384 * 64];
  int tid = threadIdx.x, wid = tid >> 6, lane = tid & 63;
  int l15 = lane & 15, l4 = lane >> 4;
  int row0 = blockIdx.x * 64;
  f32x4 zz = {0.f, 0.f, 0.f, 0.f};
  f32x4 acc[24];
  #pragma unroll
  for (int i = 0; i < 24; ++i) acc[i] = zz;

  for (int k0 = 0; k0 < 384; k0 += 64) {
    #pragma unroll
    for (int j = 0; j < 2; ++j) {
      int c = (wid * 2 + j) * 64 + lane;   // 0..511
      int r = c >> 3, kc = c & 7, kcs = kc ^ (r & 7);
      gload_lds16(A + (size_t)(row0 + r) * 384 + k0 + kcs * 8, &Ash[(wid * 2 + j) * 512]);
    }
    #pragma unroll
    for (int j = 0; j < 12; ++j) {
      int c = (wid * 12 + j) * 64 + lane;  // 0..3071
      int r = c >> 3, kc = c & 7, kcs = kc ^ (r & 7);
      gload_lds16(B + (size_t)r * 384 + k0 + kcs * 8, &Bsh[(wid * 12 + j) * 512]);
    }
    __syncthreads();
    #pragma unroll
    for (int kk = 0; kk < 2; ++kk) {
      int rr = wid * 16 + l15;
      int ch = (kk * 4 + l4) ^ (rr & 7);
      s16x8 af = *(const s16x8*)&Ash[rr * 64 + ch * 8];
      #pragma unroll
      for (int ni = 0; ni < 24; ++ni) {
        int rb = ni * 16 + l15;
        int chb = (kk * 4 + l4) ^ (rb & 7);
        s16x8 bf = *(const s16x8*)&Bsh[rb * 64 + chb * 8];
        acc[ni] = __builtin_amdgcn_mfma_f32_16x16x32_bf16(af, bf, acc[ni], 0, 0, 0);
      }
    }
    __syncthreads();
  }

  #pragma unroll
  for (int r = 0; r < 4; ++r) {
    int row = row0 + wid * 16 + l4 * 4 + r;
    float t[24];
    float s = 0.f;
    #pragma unroll
    for (int ni = 0; ni < 24; ++ni) {
      int col = ni * 16 + l15;
      float v = acc[ni][r] + bout[col] + win[(size_t)row * CDIM + col];
      t[ni] = v; s += v;
    }
    #pragma unroll
    for (int m = 1; m < 16; m <<= 1) s += __shfl_xor(s, m, 64);
    float mean = s * (1.f / 384.f);
    float s2 = 0.f;
    #pragma unroll
    for (int ni = 0; ni < 24; ++ni) { float d = t[ni] - mean; s2 += d * d; }
    #pragma unroll
    for (int m = 1; m < 16; m <<= 1) s2 += __shfl_xor(s2, m, 64);
    float rstd = rsqrtf(s2 * (1.f / 384.f) + 1e-5f);
    int orig = win_to_orig(row);
    float xn[24];
    float xs = 0.f;
    #pragma unroll
    for (int ni = 0; ni < 24; ++ni) {
      int col = ni * 16 + l15;
      float a_ln = (t[ni] - mean) * rstd * g_nout[col] + b_nout[col];
      float xv = x[(size_t)orig * CDIM + col] + a_ln;
      xn[ni] = xv; xs += xv;
    }
    #pragma unroll
    for (int m = 1; m < 16; m <<= 1) xs += __shfl_xor(xs, m, 64);
    float m2 = xs * (1.f / 384.f);
    float xs2 = 0.f;
    #pragma unroll
    for (int ni = 0; ni < 24; ++ni) { float d = xn[ni] - m2; xs2 += d * d; }
    #pragma unroll
    for (int m = 1; m < 16; m <<= 1) xs2 += __shfl_xor(xs2, m, 64);
    float rstd2 = rsqrtf(xs2 * (1.f / 384.f) + 1e-5f);
    #pragma unroll
    for (int ni = 0; ni < 24; ++ni) {
      int col = ni * 16 + l15;
      x_new[(size_t)row * CDIM + col] = xn[ni];
      xhat2[(size_t)row * CDIM + col] = f2bf((xn[ni] - m2) * rstd2);
    }
  }
}

// ---------- launch ----------

extern "C" void kernel_launch(void* const* d_in, const int* in_sizes, int n_in,
                              void* d_out, int out_size, void* d_ws, size_t ws_size,
                              hipStream_t stream) {
  const float* x    = (const float*)d_in[0];
  const float* n1g  = (const float*)d_in[1];
  const float* n1b  = (const float*)d_in[2];
  const float* nqg  = (const float*)d_in[3];
  const float* nqb  = (const float*)d_in[4];
  const float* nkg  = (const float*)d_in[5];
  const float* nkb  = (const float*)d_in[6];
  const float* nvg  = (const float*)d_in[7];
  const float* nvb  = (const float*)d_in[8];
  const float* nog  = (const float*)d_in[9];
  const float* nob  = (const float*)d_in[10];
  const float* Wqkv = (const float*)d_in[11];
  const float* bqkv = (const float*)d_in[12];
  const float* Wout = (const float*)d_in[13];
  const float* bout = (const float*)d_in[14];
  const float* n2g  = (const float*)d_in[15];
  const float* n2b  = (const float*)d_in[16];
  const float* w1   = (const float*)d_in[17];
  const float* b1   = (const float*)d_in[18];
  const float* w2   = (const float*)d_in[19];
  const float* b2   = (const float*)d_in[20];
  float* out = (float*)d_out;

  // ---- workspace layout (total ~708 MB) ----
  char* ws = (char*)d_ws;
  size_t off = 0;
  auto alloc = [&](size_t bytes) { char* p = ws + off; off += (bytes + 255) & ~255ull; return p; };
  short* Wqkv_e = (short*)alloc((size_t)1152 * 384 * 2);
  float* bqkv_e = (float*)alloc(1152 * 4);
  short* W1_e   = (short*)alloc((size_t)1536 * 384 * 2);
  float* b1_e   = (float*)alloc(1536 * 4);
  short* Wout_b = (short*)alloc((size_t)384 * 384 * 2);
  short* W2_b   = (short*)alloc((size_t)384 * 1536 * 2);
  float* win     = (float*)alloc((size_t)T_TOK * CDIM * 4);   // 201.3 MB
  short* win_hat = (short*)alloc((size_t)T_TOK * CDIM * 2);   // 100.7 MB
  short* o_buf   = (short*)alloc((size_t)T_TOK * CDIM * 2);   // 100.7 MB
  short* qkv     = (short*)alloc((size_t)T_TOK * 1152 * 2);   // 302.0 MB
  // aliases (lifetime-checked):
  short* h     = win_hat;                                     // 402.6 MB over {win_hat, o_buf, qkv[0..201.3MB)} — all dead when FFN1 runs
  short* xhat2 = (short*)((char*)qkv + (size_t)T_TOK * CDIM * 4 / 2 * 1);  // qkv tail [201.3MB..302MB) — disjoint from h's span
  float* x_new = win;                                         // in-place in K4 (see note)

  // weight prep (tiny; every call, no static state)
  k_fold<<<384, 64, 0, stream>>>(Wqkv,                 bqkv,       nqg, nqb, Wqkv_e,                 bqkv_e);
  k_fold<<<384, 64, 0, stream>>>(Wqkv + 384 * 384,     bqkv + 384, nkg, nkb, Wqkv_e + 384 * 384,     bqkv_e + 384);
  k_fold<<<384, 64, 0, stream>>>(Wqkv + 2 * 384 * 384, bqkv + 768, nvg, nvb, Wqkv_e + 2 * 384 * 384, bqkv_e + 768);
  k_fold<<<1536, 64, 0, stream>>>(w1, b1, n2g, n2b, W1_e, b1_e);
  k_conv<<<576, 256, 0, stream>>>(Wout, Wout_b, 384 * 384);
  k_conv<<<2304, 256, 0, stream>>>(w2, W2_b, 384 * 1536);

  // main pipeline
  k1_ln<<<T_TOK / 4, 256, 0, stream>>>(x, n1g, n1b, win, win_hat);
  gemm128<384, 0, 1152><<<dim3(9, 1024), 256, 0, stream>>>(win_hat, Wqkv_e, bqkv_e, qkv, nullptr);
  k3_attn<<<2048 * 3, 256, 0, stream>>>(qkv, o_buf);
  k4_outproj<<<2048, 256, 0, stream>>>(o_buf, Wout_b, bout, nog, nob, win, x, x_new, xhat2);
  gemm128<384, 1, 1536><<<dim3(12, 1024), 256, 0, stream>>>(xhat2, W1_e, b1_e, h, nullptr);
  gemm128<1536, 2, 384><<<dim3(3, 1024), 256, 0, stream>>>(h, W2_b, b2, out, x_new);
}

// Round 4
// 1438.850 us; speedup vs baseline: 1.0117x; 1.0117x over previous
//
#include <hip/hip_runtime.h>
#include <hip/hip_bf16.h>
#include <math.h>
#include <stdint.h>

#define T_TOK 131072   // 32 * 64 * 64 tokens
#define CDIM 384
#define FFDIM 1536

typedef __attribute__((ext_vector_type(4))) float f32x4;
typedef __attribute__((ext_vector_type(8))) short s16x8;

// ---------- helpers ----------

__device__ inline short f2bf(float f) {   // round-to-nearest-even f32 -> bf16 bits
  union { float f; unsigned u; } v; v.f = f;
  unsigned r = v.u + 0x7FFFu + ((v.u >> 16) & 1u);
  return (short)(r >> 16);
}

__device__ inline unsigned f2bf2(float lo, float hi) {  // pack 2 bf16 into u32
  return (unsigned)(unsigned short)f2bf(lo) | ((unsigned)(unsigned short)f2bf(hi) << 16);
}

// window-layout token index -> original (B, H*W) row index
__device__ inline int win_to_orig(int t) {
  int w = t >> 6, l = t & 63;
  int b = w >> 6, wh = (w >> 3) & 7, ww = w & 7;
  int r = l >> 3, c = l & 7;
  return (b << 12) + ((wh << 3) + r) * 64 + (ww << 3) + c;
}

__device__ inline void gload_lds16(const void* g, void* l) {
  __builtin_amdgcn_global_load_lds(
      (const __attribute__((address_space(1))) void*)g,
      (__attribute__((address_space(3))) void*)l, 16, 0, 0);
}

__device__ inline float red64(float v) {
  #pragma unroll
  for (int m = 1; m < 64; m <<= 1) v += __shfl_xor(v, m, 64);
  return v;
}

// ---------- weight prep ----------

__global__ __launch_bounds__(64) void k_fold(
    const float* __restrict__ W, const float* __restrict__ bias,
    const float* __restrict__ g, const float* __restrict__ bln,
    short* __restrict__ Weff, float* __restrict__ beff) {
  int o = blockIdx.x, lane = threadIdx.x;
  const float* wr = W + (size_t)o * CDIM;
  float s = 0.f;
  #pragma unroll
  for (int j = 0; j < 6; ++j) {
    int c = j * 64 + lane;
    float wv = wr[c];
    Weff[(size_t)o * CDIM + c] = f2bf(wv * g[c]);
    s += wv * bln[c];
  }
  s = red64(s);
  if (lane == 0) beff[o] = bias[o] + s;
}

__global__ void k_conv(const float* __restrict__ a, short* __restrict__ o, int n) {
  int i = blockIdx.x * 256 + threadIdx.x;
  if (i < n) o[i] = f2bf(a[i]);
}

// ---------- K1: LN1 (window gather) + shared LN-hat for q/k/v ----------

__global__ __launch_bounds__(256) void k1_ln(
    const float* __restrict__ x, const float* __restrict__ g1, const float* __restrict__ b1,
    float* __restrict__ win, short* __restrict__ win_hat) {
  int wid = threadIdx.x >> 6, lane = threadIdx.x & 63;
  int t = blockIdx.x * 4 + wid;
  int orig = win_to_orig(t);
  const float* xr = x + (size_t)orig * CDIM;
  float2 v[3];
  float s = 0.f;
  #pragma unroll
  for (int j = 0; j < 3; ++j) {
    v[j] = *(const float2*)&xr[j * 128 + lane * 2];
    s += v[j].x + v[j].y;
  }
  s = red64(s);
  float m = s * (1.f / 384.f);
  float s2 = 0.f;
  #pragma unroll
  for (int j = 0; j < 3; ++j) {
    float dx = v[j].x - m, dy = v[j].y - m;
    s2 += dx * dx + dy * dy;
  }
  s2 = red64(s2);
  float rstd = rsqrtf(s2 * (1.f / 384.f) + 1e-5f);
  float2 wv[3]; float sw = 0.f;
  #pragma unroll
  for (int j = 0; j < 3; ++j) {
    int c = j * 128 + lane * 2;
    float2 g = *(const float2*)&g1[c];
    float2 b = *(const float2*)&b1[c];
    wv[j].x = (v[j].x - m) * rstd * g.x + b.x;
    wv[j].y = (v[j].y - m) * rstd * g.y + b.y;
    sw += wv[j].x + wv[j].y;
  }
  sw = red64(sw);
  float m2 = sw * (1.f / 384.f);
  float s2b = 0.f;
  #pragma unroll
  for (int j = 0; j < 3; ++j) {
    float dx = wv[j].x - m2, dy = wv[j].y - m2;
    s2b += dx * dx + dy * dy;
  }
  s2b = red64(s2b);
  float rstd2 = rsqrtf(s2b * (1.f / 384.f) + 1e-5f);
  float* wr = win + (size_t)t * CDIM;
  short* whr = win_hat + (size_t)t * CDIM;
  #pragma unroll
  for (int j = 0; j < 3; ++j) {
    int c = j * 128 + lane * 2;
    *(float2*)&wr[c] = wv[j];
    *(unsigned*)&whr[c] = f2bf2((wv[j].x - m2) * rstd2, (wv[j].y - m2) * rstd2);
  }
}

// ---------- generic 128x128 MFMA GEMM:  C[M,N] = A[M,K] @ B[N,K]^T ----------
// Operand-SWAPPED mfma (B in A-slot): lane holds 1 out-row x 4 consecutive cols
// -> vectorized epilogue (uint2 bf16x4 / float4 stores, float4 bias/resid loads).
// XCD swizzle: consecutive same-XCD blocks (bid%8 const) share an A row-panel.
// EPI 0: bf16 out = acc + bias           (QKV)
// EPI 1: bf16 out = gelu(acc + bias)     (FFN1)
// EPI 2: f32 d_out[perm(row)] = acc + bias + resid[row]   (FFN2)

template <int K, int EPI, int LDO, int NBX>
__global__ __launch_bounds__(256, 2) void gemm128(
    const short* __restrict__ A, const short* __restrict__ B,
    const float* __restrict__ bias, void* __restrict__ out,
    const float* __restrict__ resid) {
  __shared__ short Ash[128 * 64];
  __shared__ short Bsh[128 * 64];
  int tid = threadIdx.x;
  int wid = tid >> 6, lane = tid & 63;
  int l15 = lane & 15, l4 = lane >> 4;
  // XCD-aware swizzle (nwg = NBX*1024, divisible by 8)
  constexpr int cpx = NBX * 128;
  int lb = ((int)blockIdx.x & 7) * cpx + ((int)blockIdx.x >> 3);
  int bx = lb % NBX, by = lb / NBX;
  int row0 = by * 128, col0 = bx * 128;
  int wr = (wid >> 1) * 64, wc = (wid & 1) * 64;
  f32x4 zz = {0.f, 0.f, 0.f, 0.f};
  f32x4 acc[4][4];
  #pragma unroll
  for (int a = 0; a < 4; ++a)
    #pragma unroll
    for (int b = 0; b < 4; ++b) acc[a][b] = zz;

  for (int k0 = 0; k0 < K; k0 += 64) {
    #pragma unroll
    for (int j = 0; j < 4; ++j) {
      int c = (wid * 4 + j) * 64 + lane;     // chunk id 0..1023 (16B chunks)
      int r = c >> 3, kc = c & 7;
      int kcs = kc ^ (r & 7);                // source pre-swizzle (rule 21)
      gload_lds16(A + (size_t)(row0 + r) * K + k0 + kcs * 8, &Ash[(wid * 4 + j) * 512]);
      gload_lds16(B + (size_t)(col0 + r) * K + k0 + kcs * 8, &Bsh[(wid * 4 + j) * 512]);
    }
    __syncthreads();
    #pragma unroll
    for (int kk = 0; kk < 2; ++kk) {
      s16x8 af[4], bfr[4];
      #pragma unroll
      for (int mi = 0; mi < 4; ++mi) {
        int rr = wr + mi * 16 + l15;
        int ch = (kk * 4 + l4) ^ (rr & 7);
        af[mi] = *(const s16x8*)&Ash[rr * 64 + ch * 8];
      }
      #pragma unroll
      for (int ni = 0; ni < 4; ++ni) {
        int rr = wc + ni * 16 + l15;
        int ch = (kk * 4 + l4) ^ (rr & 7);
        bfr[ni] = *(const s16x8*)&Bsh[rr * 64 + ch * 8];
      }
      #pragma unroll
      for (int mi = 0; mi < 4; ++mi)
        #pragma unroll
        for (int ni = 0; ni < 4; ++ni)
          acc[mi][ni] = __builtin_amdgcn_mfma_f32_16x16x32_bf16(bfr[ni], af[mi], acc[mi][ni], 0, 0, 0);
    }
    __syncthreads();
  }

  // swapped layout: out_row = l15 (per mi tile), out_cols = l4*4 + 0..3 (per ni tile)
  #pragma unroll
  for (int mi = 0; mi < 4; ++mi) {
    int row = row0 + wr + mi * 16 + l15;
    int orow = (EPI == 2) ? win_to_orig(row) : row;
    #pragma unroll
    for (int ni = 0; ni < 4; ++ni) {
      int col = col0 + wc + ni * 16 + l4 * 4;
      float4 b4 = *(const float4*)&bias[col];
      float v0 = acc[mi][ni][0] + b4.x;
      float v1 = acc[mi][ni][1] + b4.y;
      float v2 = acc[mi][ni][2] + b4.z;
      float v3 = acc[mi][ni][3] + b4.w;
      if constexpr (EPI == 0) {
        uint2 p; p.x = f2bf2(v0, v1); p.y = f2bf2(v2, v3);
        *(uint2*)&((short*)out)[(size_t)row * LDO + col] = p;
      } else if constexpr (EPI == 1) {
        v0 = 0.5f * v0 * (1.f + erff(v0 * 0.70710678118654752f));
        v1 = 0.5f * v1 * (1.f + erff(v1 * 0.70710678118654752f));
        v2 = 0.5f * v2 * (1.f + erff(v2 * 0.70710678118654752f));
        v3 = 0.5f * v3 * (1.f + erff(v3 * 0.70710678118654752f));
        uint2 p; p.x = f2bf2(v0, v1); p.y = f2bf2(v2, v3);
        *(uint2*)&((short*)out)[(size_t)row * LDO + col] = p;
      } else {
        const float4 r4 = *(const float4*)&resid[(size_t)row * CDIM + col];
        float4 o4; o4.x = v0 + r4.x; o4.y = v1 + r4.y; o4.z = v2 + r4.z; o4.w = v3 + r4.w;
        *(float4*)&((float*)out)[(size_t)orow * CDIM + col] = o4;
      }
    }
  }
}

// ---------- K3: windowed attention, one wave = one (window, head) ----------

__global__ __launch_bounds__(256, 2) void k3_attn(
    const short* __restrict__ qkv, short* __restrict__ o) {
  __shared__ short Psh[4][64 * 72];   // P, padded stride 72 (bank-conflict-free)
  __shared__ short Vsh[4][32 * 72];   // V^T
  int tid = threadIdx.x, wid = tid >> 6, lane = tid & 63;
  int l15 = lane & 15, l4 = lane >> 4;
  int w = blockIdx.x / 3, q3 = blockIdx.x % 3;
  int h = q3 * 4 + wid;
  const short* base = qkv + (size_t)w * 64 * 1152;

  s16x8 qf[4], kf[4];
  #pragma unroll
  for (int i = 0; i < 4; ++i) {
    qf[i] = *(const s16x8*)&base[(size_t)(i * 16 + l15) * 1152 + h * 32 + l4 * 8];
    kf[i] = *(const s16x8*)&base[(size_t)(i * 16 + l15) * 1152 + 384 + h * 32 + l4 * 8];
  }
  f32x4 zz = {0.f, 0.f, 0.f, 0.f};
  f32x4 s[4][4];
  #pragma unroll
  for (int a = 0; a < 4; ++a)
    #pragma unroll
    for (int b = 0; b < 4; ++b) s[a][b] = zz;
  #pragma unroll
  for (int mi = 0; mi < 4; ++mi)
    #pragma unroll
    for (int ni = 0; ni < 4; ++ni)
      s[mi][ni] = __builtin_amdgcn_mfma_f32_16x16x32_bf16(qf[mi], kf[ni], s[mi][ni], 0, 0, 0);

  const float scale = 0.17677669529663687f;  // 1/sqrt(32)
  float rs[4][4];
  #pragma unroll
  for (int mi = 0; mi < 4; ++mi)
    #pragma unroll
    for (int r = 0; r < 4; ++r) {
      float mx = -1e30f;
      #pragma unroll
      for (int ni = 0; ni < 4; ++ni) { s[mi][ni][r] *= scale; mx = fmaxf(mx, s[mi][ni][r]); }
      #pragma unroll
      for (int m = 1; m < 16; m <<= 1) mx = fmaxf(mx, __shfl_xor(mx, m, 64));
      float sum = 0.f;
      int prow = mi * 16 + l4 * 4 + r;
      #pragma unroll
      for (int ni = 0; ni < 4; ++ni) {
        float p = __expf(s[mi][ni][r] - mx);
        sum += p;
        Psh[wid][prow * 72 + ni * 16 + l15] = f2bf(p);
      }
      #pragma unroll
      for (int m = 1; m < 16; m <<= 1) sum += __shfl_xor(sum, m, 64);
      rs[mi][r] = 1.f / sum;
    }

  {  // stage V transposed: Vsh[d][t]
    const short* vr = base + (size_t)lane * 1152 + 768 + h * 32;
    s16x8 v0 = *(const s16x8*)vr;
    s16x8 v1 = *(const s16x8*)(vr + 8);
    s16x8 v2 = *(const s16x8*)(vr + 16);
    s16x8 v3 = *(const s16x8*)(vr + 24);
    #pragma unroll
    for (int d = 0; d < 8; ++d) {
      Vsh[wid][d * 72 + lane] = v0[d];
      Vsh[wid][(d + 8) * 72 + lane] = v1[d];
      Vsh[wid][(d + 16) * 72 + lane] = v2[d];
      Vsh[wid][(d + 24) * 72 + lane] = v3[d];
    }
  }
  __syncthreads();

  f32x4 oacc[4][2];
  #pragma unroll
  for (int a = 0; a < 4; ++a) { oacc[a][0] = zz; oacc[a][1] = zz; }
  #pragma unroll
  for (int kk = 0; kk < 2; ++kk) {
    s16x8 pa[4], vb[2];
    #pragma unroll
    for (int mi = 0; mi < 4; ++mi)
      pa[mi] = *(const s16x8*)&Psh[wid][(mi * 16 + l15) * 72 + kk * 32 + l4 * 8];
    #pragma unroll
    for (int ni = 0; ni < 2; ++ni)
      vb[ni] = *(const s16x8*)&Vsh[wid][(ni * 16 + l15) * 72 + kk * 32 + l4 * 8];
    #pragma unroll
    for (int mi = 0; mi < 4; ++mi)
      #pragma unroll
      for (int ni = 0; ni < 2; ++ni)
        oacc[mi][ni] = __builtin_amdgcn_mfma_f32_16x16x32_bf16(pa[mi], vb[ni], oacc[mi][ni], 0, 0, 0);
  }
  #pragma unroll
  for (int mi = 0; mi < 4; ++mi)
    #pragma unroll
    for (int ni = 0; ni < 2; ++ni)
      #pragma unroll
      for (int r = 0; r < 4; ++r) {
        int row = mi * 16 + l4 * 4 + r;
        float val = oacc[mi][ni][r] * rs[mi][r];
        o[((size_t)w * 64 + row) * 384 + h * 32 + ni * 16 + l15] = f2bf(val);
      }
}

// ---------- K4: out_proj GEMM (BN=384 full row) + nout LN + x-residual + norm2-hat ----------
// Swapped-operand MFMA: each lane owns ONE row (l15) x 96 cols (l4*4+r per ni).
// Row-LN reduce = local 96-sum + shfl_xor(16) + shfl_xor(32).
// win/x_new ALIAS (in-place): safe — reads precede writes in-wave with data dep.

__global__ __launch_bounds__(256, 2) void k4_outproj(
    const short* __restrict__ A, const short* __restrict__ B,
    const float* __restrict__ bout, const float* __restrict__ g_nout, const float* __restrict__ b_nout,
    const float* win, const float* __restrict__ x,
    float* x_new, short* __restrict__ xhat2) {
  __shared__ short Ash[64 * 64];
  __shared__ short Bsh[384 * 64];
  int tid = threadIdx.x, wid = tid >> 6, lane = tid & 63;
  int l15 = lane & 15, l4 = lane >> 4;
  int row0 = blockIdx.x * 64;
  f32x4 zz = {0.f, 0.f, 0.f, 0.f};
  f32x4 acc[24];
  #pragma unroll
  for (int i = 0; i < 24; ++i) acc[i] = zz;

  for (int k0 = 0; k0 < 384; k0 += 64) {
    #pragma unroll
    for (int j = 0; j < 2; ++j) {
      int c = (wid * 2 + j) * 64 + lane;   // 0..511
      int r = c >> 3, kc = c & 7, kcs = kc ^ (r & 7);
      gload_lds16(A + (size_t)(row0 + r) * 384 + k0 + kcs * 8, &Ash[(wid * 2 + j) * 512]);
    }
    #pragma unroll
    for (int j = 0; j < 12; ++j) {
      int c = (wid * 12 + j) * 64 + lane;  // 0..3071
      int r = c >> 3, kc = c & 7, kcs = kc ^ (r & 7);
      gload_lds16(B + (size_t)r * 384 + k0 + kcs * 8, &Bsh[(wid * 12 + j) * 512]);
    }
    __syncthreads();
    #pragma unroll
    for (int kk = 0; kk < 2; ++kk) {
      int rr = wid * 16 + l15;
      int ch = (kk * 4 + l4) ^ (rr & 7);
      s16x8 af = *(const s16x8*)&Ash[rr * 64 + ch * 8];
      #pragma unroll
      for (int ni = 0; ni < 24; ++ni) {
        int rb = ni * 16 + l15;
        int chb = (kk * 4 + l4) ^ (rb & 7);
        s16x8 bf = *(const s16x8*)&Bsh[rb * 64 + chb * 8];
        acc[ni] = __builtin_amdgcn_mfma_f32_16x16x32_bf16(bf, af, acc[ni], 0, 0, 0);
      }
    }
    __syncthreads();
  }

  int row = row0 + wid * 16 + l15;
  int cb = l4 * 4;
  // acc += bias + win (f32, vectorized); first LN stats
  float s = 0.f;
  #pragma unroll
  for (int ni = 0; ni < 24; ++ni) {
    int col = ni * 16 + cb;
    float4 b4 = *(const float4*)&bout[col];
    float4 w4 = *(const float4*)&win[(size_t)row * CDIM + col];
    acc[ni][0] += b4.x + w4.x;
    acc[ni][1] += b4.y + w4.y;
    acc[ni][2] += b4.z + w4.z;
    acc[ni][3] += b4.w + w4.w;
    s += acc[ni][0] + acc[ni][1] + acc[ni][2] + acc[ni][3];
  }
  s += __shfl_xor(s, 16, 64); s += __shfl_xor(s, 32, 64);
  float mean = s * (1.f / 384.f);
  float s2 = 0.f;
  #pragma unroll
  for (int ni = 0; ni < 24; ++ni) {
    #pragma unroll
    for (int r = 0; r < 4; ++r) { float d = acc[ni][r] - mean; s2 += d * d; }
  }
  s2 += __shfl_xor(s2, 16, 64); s2 += __shfl_xor(s2, 32, 64);
  float rstd = rsqrtf(s2 * (1.f / 384.f) + 1e-5f);
  int orig = win_to_orig(row);
  // acc <- x + LN(acc); second LN stats
  float xs = 0.f;
  #pragma unroll
  for (int ni = 0; ni < 24; ++ni) {
    int col = ni * 16 + cb;
    float4 g4 = *(const float4*)&g_nout[col];
    float4 bb = *(const float4*)&b_nout[col];
    float4 x4 = *(const float4*)&x[(size_t)orig * CDIM + col];
    acc[ni][0] = x4.x + (acc[ni][0] - mean) * rstd * g4.x + bb.x;
    acc[ni][1] = x4.y + (acc[ni][1] - mean) * rstd * g4.y + bb.y;
    acc[ni][2] = x4.z + (acc[ni][2] - mean) * rstd * g4.z + bb.z;
    acc[ni][3] = x4.w + (acc[ni][3] - mean) * rstd * g4.w + bb.w;
    xs += acc[ni][0] + acc[ni][1] + acc[ni][2] + acc[ni][3];
  }
  xs += __shfl_xor(xs, 16, 64); xs += __shfl_xor(xs, 32, 64);
  float m2 = xs * (1.f / 384.f);
  float xs2 = 0.f;
  #pragma unroll
  for (int ni = 0; ni < 24; ++ni) {
    #pragma unroll
    for (int r = 0; r < 4; ++r) { float d = acc[ni][r] - m2; xs2 += d * d; }
  }
  xs2 += __shfl_xor(xs2, 16, 64); xs2 += __shfl_xor(xs2, 32, 64);
  float rstd2 = rsqrtf(xs2 * (1.f / 384.f) + 1e-5f);
  #pragma unroll
  for (int ni = 0; ni < 24; ++ni) {
    int col = ni * 16 + cb;
    float4 o4; o4.x = acc[ni][0]; o4.y = acc[ni][1]; o4.z = acc[ni][2]; o4.w = acc[ni][3];
    *(float4*)&x_new[(size_t)row * CDIM + col] = o4;
    uint2 p;
    p.x = f2bf2((acc[ni][0] - m2) * rstd2, (acc[ni][1] - m2) * rstd2);
    p.y = f2bf2((acc[ni][2] - m2) * rstd2, (acc[ni][3] - m2) * rstd2);
    *(uint2*)&xhat2[(size_t)row * CDIM + col] = p;
  }
}

// ---------- launch ----------

extern "C" void kernel_launch(void* const* d_in, const int* in_sizes, int n_in,
                              void* d_out, int out_size, void* d_ws, size_t ws_size,
                              hipStream_t stream) {
  const float* x    = (const float*)d_in[0];
  const float* n1g  = (const float*)d_in[1];
  const float* n1b  = (const float*)d_in[2];
  const float* nqg  = (const float*)d_in[3];
  const float* nqb  = (const float*)d_in[4];
  const float* nkg  = (const float*)d_in[5];
  const float* nkb  = (const float*)d_in[6];
  const float* nvg  = (const float*)d_in[7];
  const float* nvb  = (const float*)d_in[8];
  const float* nog  = (const float*)d_in[9];
  const float* nob  = (const float*)d_in[10];
  const float* Wqkv = (const float*)d_in[11];
  const float* bqkv = (const float*)d_in[12];
  const float* Wout = (const float*)d_in[13];
  const float* bout = (const float*)d_in[14];
  const float* n2g  = (const float*)d_in[15];
  const float* n2b  = (const float*)d_in[16];
  const float* w1   = (const float*)d_in[17];
  const float* b1   = (const float*)d_in[18];
  const float* w2   = (const float*)d_in[19];
  const float* b2   = (const float*)d_in[20];
  float* out = (float*)d_out;

  // ---- workspace layout (total ~708 MB) ----
  // absolute spans (MB): win [0,201.3) | win_hat [201.3,302.0) | o_buf [302.0,402.7)
  //                      | qkv [402.7,704.7)
  // h     = win_hat..+402.6MB = [201.3,603.9)   (win_hat, o_buf, qkv head — all dead at FFN1)
  // xhat2 = qkv+201.3MB       = [604.0,704.7)   (qkv tail third — DISJOINT from h; the round-3
  //                                              failure was xhat2 at qkv+100.7MB inside h's span)
  char* ws = (char*)d_ws;
  size_t off = 0;
  auto alloc = [&](size_t bytes) { char* p = ws + off; off += (bytes + 255) & ~255ull; return p; };
  short* Wqkv_e = (short*)alloc((size_t)1152 * 384 * 2);
  float* bqkv_e = (float*)alloc(1152 * 4);
  short* W1_e   = (short*)alloc((size_t)1536 * 384 * 2);
  float* b1_e   = (float*)alloc(1536 * 4);
  short* Wout_b = (short*)alloc((size_t)384 * 384 * 2);
  short* W2_b   = (short*)alloc((size_t)384 * 1536 * 2);
  float* win     = (float*)alloc((size_t)T_TOK * CDIM * 4);   // 201.3 MB
  short* win_hat = (short*)alloc((size_t)T_TOK * CDIM * 2);   // 100.7 MB
  short* o_buf   = (short*)alloc((size_t)T_TOK * CDIM * 2);   // 100.7 MB
  short* qkv     = (short*)alloc((size_t)T_TOK * 1152 * 2);   // 302.0 MB
  // aliases (lifetime-checked):
  short* h     = win_hat;                                        // [201.3,603.9)
  short* xhat2 = (short*)((char*)qkv + (size_t)T_TOK * CDIM * 4); // [604.0,704.7) — true qkv tail
  float* x_new = win;                                            // in-place in K4 (see note)

  // weight prep (tiny; every call, no static state)
  k_fold<<<384, 64, 0, stream>>>(Wqkv,                 bqkv,       nqg, nqb, Wqkv_e,                 bqkv_e);
  k_fold<<<384, 64, 0, stream>>>(Wqkv + 384 * 384,     bqkv + 384, nkg, nkb, Wqkv_e + 384 * 384,     bqkv_e + 384);
  k_fold<<<384, 64, 0, stream>>>(Wqkv + 2 * 384 * 384, bqkv + 768, nvg, nvb, Wqkv_e + 2 * 384 * 384, bqkv_e + 768);
  k_fold<<<1536, 64, 0, stream>>>(w1, b1, n2g, n2b, W1_e, b1_e);
  k_conv<<<576, 256, 0, stream>>>(Wout, Wout_b, 384 * 384);
  k_conv<<<2304, 256, 0, stream>>>(w2, W2_b, 384 * 1536);

  // main pipeline (gemm128 grids are 1D, XCD-swizzled internally)
  k1_ln<<<T_TOK / 4, 256, 0, stream>>>(x, n1g, n1b, win, win_hat);
  gemm128<384, 0, 1152, 9><<<9 * 1024, 256, 0, stream>>>(win_hat, Wqkv_e, bqkv_e, qkv, nullptr);
  k3_attn<<<2048 * 3, 256, 0, stream>>>(qkv, o_buf);
  k4_outproj<<<2048, 256, 0, stream>>>(o_buf, Wout_b, bout, nog, nob, win, x, x_new, xhat2);
  gemm128<384, 1, 1536, 12><<<12 * 1024, 256, 0, stream>>>(xhat2, W1_e, b1_e, h, nullptr);
  gemm128<1536, 2, 384, 3><<<3 * 1024, 256, 0, stream>>>(h, W2_b, b2, out, x_new);
}